// Round 7
// baseline (205.532 us; speedup 1.0000x reference)
//
#include <hip/hip_runtime.h>
#include <math.h>

#define NN 8192
#define DD 128
#define JR 32                    // j-ranges; each block covers 256 cols
#define NT ((NN / JR) / 64)      // 4 tiles of 64 cols per block
#define SQKE 3.7982825f          // sqrt(10*log2(e)); xn pre-scaled -> MFMA emits exp2-ready logits
#define LN2 0.6931471805599453f
#define NCLS 33

typedef __attribute__((ext_vector_type(8))) short short8;
typedef __attribute__((ext_vector_type(4))) float f32x4;

__device__ __forceinline__ unsigned short f2bf(float f) {
    unsigned u = __builtin_bit_cast(unsigned, f);
    unsigned r = (u + 0x7FFFu + ((u >> 16) & 1u)) >> 16;
    return (unsigned short)r;
}
__device__ __forceinline__ float bf2f(unsigned short h) {
    unsigned u = ((unsigned)h) << 16;
    return __builtin_bit_cast(float, u);
}

// ---- kernel 1: normalize+scale rows -> bf16, selfdot; zero Z/S/psum/pcnt ----
__global__ __launch_bounds__(256) void prep_kernel(const float* __restrict__ x,
                                                   unsigned short* __restrict__ xn,
                                                   float* __restrict__ sd,
                                                   float* __restrict__ zs) {
    const int b = blockIdx.x, t = threadIdx.x;
    const int zi = b * 256 + t;
    if (zi < 2 * NN + 64) zs[zi] = 0.f;          // Z[NN] S[NN] psum[32] pcnt[32]

    int row  = (b << 2) + (t >> 6);
    int lane = t & 63;
    float2 v = ((const float2*)(x + (size_t)row * DD))[lane];
    float ss = v.x * v.x + v.y * v.y;
    #pragma unroll
    for (int off = 32; off; off >>= 1) ss += __shfl_xor(ss, off);
    float rs = rsqrtf(ss) * SQKE;
    unsigned short bx = f2bf(v.x * rs), by = f2bf(v.y * rs);
    ushort2 st; st.x = bx; st.y = by;
    ((ushort2*)(xn + (size_t)row * DD))[lane] = st;
    float fx = bf2f(bx), fy = bf2f(by);
    float s2 = fx * fx + fy * fy;
    #pragma unroll
    for (int off = 32; off; off >>= 1) s2 += __shfl_xor(s2, off);
    if (lane == 0) sd[row] = s2;
}

// ---- kernel 2: MFMA similarity; LDS-shared B tile, double-buffered ----
// 512 thr = 8 waves; wave owns 64 rows; block covers 512 rows x 256 cols.
// Grid 512 = 2 blocks/CU = 4 waves/SIMD: co-resident block fills barrier bubbles.
__global__ __launch_bounds__(512, 4) void cl_main(const unsigned short* __restrict__ xn,
                                                  const int* __restrict__ labels,
                                                  float* __restrict__ Z,
                                                  float* __restrict__ S) {
    __shared__ __align__(16) unsigned short Bt[2][64][DD];   // 32 KB double buffer

    const int tid  = threadIdx.x;
    const int w    = tid >> 6;
    const int lane = tid & 63;
    const int l15  = lane & 15;
    const int lhi  = lane >> 4;
    const int b    = (int)blockIdx.x;
    const int jr   = b & (JR - 1);
    const int panel = b >> 5;                  // 0..15
    const int row0  = panel * 512 + w * 64;
    const int j0r   = jr * (NN / JR);

    // A frags: lane holds A[row0 + mi*16 + l15][ks*32 + lhi*8 .. +7]
    short8 a[4][4];
    #pragma unroll
    for (int mi = 0; mi < 4; ++mi)
        #pragma unroll
        for (int ks = 0; ks < 4; ++ks)
            a[mi][ks] = *(const short8*)(xn + (size_t)(row0 + mi * 16 + l15) * DD + ks * 32 + lhi * 8);

    int labI[4][4];
    #pragma unroll
    for (int mi = 0; mi < 4; ++mi)
        #pragma unroll
        for (int r = 0; r < 4; ++r)
            labI[mi][r] = labels[row0 + mi * 16 + lhi * 4 + r];

    // staging roles: wave w stages tile rows w*8 .. w*8+7 (two quads of 4 rows)
    // swizzle: LDS slot (row,k) holds global colblk k^(row&7)  (involution)
    const int r4 = lane >> 4, kk = lane & 15;
    const int srow0 = w * 8 + r4;
    const int srow1 = w * 8 + 4 + r4;
    const unsigned short* sg0 = xn + (size_t)(j0r + srow0) * DD + (kk ^ (srow0 & 7)) * 8;
    const unsigned short* sg1 = xn + (size_t)(j0r + srow1) * DD + (kk ^ (srow1 & 7)) * 8;

    float z[4][4], s[4][4];
    #pragma unroll
    for (int mi = 0; mi < 4; ++mi)
        #pragma unroll
        for (int r = 0; r < 4; ++r) { z[mi][r] = 0.f; s[mi][r] = 0.f; }

    // prologue: stage tile 0
    {
        short8 t0 = *(const short8*)sg0;
        short8 t1 = *(const short8*)sg1;
        *(short8*)&Bt[0][srow0][kk * 8] = t0;
        *(short8*)&Bt[0][srow1][kk * 8] = t1;
    }
    __syncthreads();

    const int sw = l15 & 7;
    int cur = 0;
    for (int t8 = 0; t8 < NT; ++t8) {
        const int j0 = j0r + t8 * 64;

        // phase A: issue next tile's global loads (latency hides under compute)
        short8 nx0, nx1;
        if (t8 < NT - 1) {
            nx0 = *(const short8*)(sg0 + (size_t)(t8 + 1) * 64 * DD);
            nx1 = *(const short8*)(sg1 + (size_t)(t8 + 1) * 64 * DD);
        }
        int lj[4];
        #pragma unroll
        for (int ni = 0; ni < 4; ++ni) lj[ni] = labels[j0 + ni * 16 + l15];

        // phase B: compute from Bt[cur]
        const char* rbase = (const char*)&Bt[cur][0][0] + l15 * 256;
        f32x4 acc[4][4];
        #pragma unroll
        for (int mi = 0; mi < 4; ++mi)
            #pragma unroll
            for (int ni = 0; ni < 4; ++ni) acc[mi][ni] = (f32x4){0.f, 0.f, 0.f, 0.f};

        #pragma unroll
        for (int ni = 0; ni < 4; ++ni) {
            short8 bfv[4];
            #pragma unroll
            for (int ks = 0; ks < 4; ++ks)
                bfv[ks] = *(const short8*)(rbase + ni * 4096 + ((((ks << 2) | lhi) ^ sw) << 4));
            #pragma unroll
            for (int ks = 0; ks < 4; ++ks)
                #pragma unroll
                for (int mi = 0; mi < 4; ++mi)
                    acc[mi][ni] = __builtin_amdgcn_mfma_f32_16x16x32_bf16(a[mi][ks], bfv[ks], acc[mi][ni], 0, 0, 0);
        }

        // epilogue: Z += exp2(d); S += d on label match (self removed in fin1)
        #pragma unroll
        for (int mi = 0; mi < 4; ++mi)
            #pragma unroll
            for (int ni = 0; ni < 4; ++ni)
                #pragma unroll
                for (int r = 0; r < 4; ++r) {
                    float d = acc[mi][ni][r];
                    z[mi][r] += __builtin_amdgcn_exp2f(d);
                    s[mi][r] += (lj[ni] == labI[mi][r]) ? d : 0.f;
                }

        // phase C: write staged data into the other buffer
        if (t8 < NT - 1) {
            *(short8*)&Bt[cur ^ 1][srow0][kk * 8] = nx0;
            *(short8*)&Bt[cur ^ 1][srow1][kk * 8] = nx1;
        }
        __syncthreads();
        cur ^= 1;
    }

    // reduce across the 16 col-lanes per row; atomically add into Z/S
    #pragma unroll
    for (int mi = 0; mi < 4; ++mi)
        #pragma unroll
        for (int r = 0; r < 4; ++r) {
            float zz = z[mi][r], ss = s[mi][r];
            #pragma unroll
            for (int off = 1; off < 16; off <<= 1) {
                zz += __shfl_xor(zz, off);
                ss += __shfl_xor(ss, off);
            }
            if (l15 == 0) {
                int row = row0 + mi * 16 + lhi * 4 + r;
                atomicAdd(&Z[row], zz);
                atomicAdd(&S[row], ss);
            }
        }
}

// ---- kernel 3: per-row finalize + per-block partial loss ----
__global__ __launch_bounds__(256) void fin1(const float* __restrict__ Z,
                                            const float* __restrict__ S,
                                            const float* __restrict__ sd,
                                            const int* __restrict__ labels,
                                            float* __restrict__ psum,
                                            float* __restrict__ pcnt) {
    __shared__ int cnt[NCLS];
    __shared__ float rs[4], rc[4];
    const int t = threadIdx.x;
    if (t < NCLS) cnt[t] = 0;
    __syncthreads();
    for (int i = t; i < NN; i += 256) atomicAdd(&cnt[labels[i]], 1);
    __syncthreads();

    const int row = blockIdx.x * 256 + t;
    float Zr = Z[row] - __builtin_amdgcn_exp2f(sd[row]);   // remove self from denominator
    float Sr = S[row] - sd[row];                           // remove self from positive-sum
    int C = cnt[labels[row]] - 1;
    float pr = 0.f, vl = 0.f;
    if (C > 0) { pr = LN2 * Sr / (float)C - logf(Zr); vl = 1.f; }
    #pragma unroll
    for (int off = 32; off; off >>= 1) { pr += __shfl_xor(pr, off); vl += __shfl_xor(vl, off); }
    int wv = t >> 6, ln = t & 63;
    if (ln == 0) { rs[wv] = pr; rc[wv] = vl; }
    __syncthreads();
    if (t == 0) {
        psum[blockIdx.x] = rs[0] + rs[1] + rs[2] + rs[3];
        pcnt[blockIdx.x] = rc[0] + rc[1] + rc[2] + rc[3];
    }
}

__global__ void fin2(const float* __restrict__ psum, const float* __restrict__ pcnt,
                     float* __restrict__ out) {
    int t = threadIdx.x;
    float a = t < 32 ? psum[t] : 0.f;
    float c = t < 32 ? pcnt[t] : 0.f;
    #pragma unroll
    for (int off = 32; off; off >>= 1) { a += __shfl_xor(a, off); c += __shfl_xor(c, off); }
    if (t == 0) out[0] = -a / c;
}

extern "C" void kernel_launch(void* const* d_in, const int* in_sizes, int n_in,
                              void* d_out, int out_size, void* d_ws, size_t ws_size,
                              hipStream_t stream) {
    const float* x      = (const float*)d_in[0];
    const int*   labels = (const int*)d_in[1];
    float* out = (float*)d_out;
    char*  ws  = (char*)d_ws;

    size_t off = 0;
    unsigned short* xn = (unsigned short*)(ws + off); off += (size_t)NN * DD * 2;  // 2 MB
    float* sd = (float*)(ws + off); off += (size_t)NN * 4;                         // 32 KB
    float* zs = (float*)(ws + off); off += (size_t)(2 * NN + 64) * 4;              // 64.25 KB
    float* Z    = zs;
    float* S    = zs + NN;
    float* psum = zs + 2 * NN;
    float* pcnt = zs + 2 * NN + 32;

    prep_kernel<<<NN / 4, 256, 0, stream>>>(x, xn, sd, zs);
    cl_main<<<(NN / 512) * JR, 512, 0, stream>>>(xn, labels, Z, S);
    fin1<<<NN / 256, 256, 0, stream>>>(Z, S, sd, labels, psum, pcnt);
    fin2<<<1, 64, 0, stream>>>(psum, pcnt, out);
}

// Round 8
// 104.246 us; speedup vs baseline: 1.9716x; 1.9716x over previous
//
#include <hip/hip_runtime.h>
#include <math.h>

#define NN 8192
#define DD 128
#define JR 32                    // j-ranges; each block covers 256 cols
#define NT ((NN / JR) / 64)      // 4 tiles of 64 cols per block
#define SQKE 3.7982825f          // sqrt(10*log2(e)); xn pre-scaled -> MFMA emits exp2-ready logits
#define LN2 0.6931471805599453f
#define NCLS 33

typedef __attribute__((ext_vector_type(8))) short short8;
typedef __attribute__((ext_vector_type(4))) float f32x4;

__device__ __forceinline__ unsigned short f2bf(float f) {
    unsigned u = __builtin_bit_cast(unsigned, f);
    unsigned r = (u + 0x7FFFu + ((u >> 16) & 1u)) >> 16;
    return (unsigned short)r;
}
__device__ __forceinline__ float bf2f(unsigned short h) {
    unsigned u = ((unsigned)h) << 16;
    return __builtin_bit_cast(float, u);
}

// ---- kernel 1: normalize+scale rows -> bf16, selfdot; zero Z/S/psum/pcnt ----
__global__ __launch_bounds__(256) void prep_kernel(const float* __restrict__ x,
                                                   unsigned short* __restrict__ xn,
                                                   float* __restrict__ sd,
                                                   float* __restrict__ zs) {
    const int b = blockIdx.x, t = threadIdx.x;
    const int zi = b * 256 + t;
    if (zi < 2 * NN + 64) zs[zi] = 0.f;          // Z[NN] S[NN] psum[32] pcnt[32]

    int row  = (b << 2) + (t >> 6);
    int lane = t & 63;
    float2 v = ((const float2*)(x + (size_t)row * DD))[lane];
    float ss = v.x * v.x + v.y * v.y;
    #pragma unroll
    for (int off = 32; off; off >>= 1) ss += __shfl_xor(ss, off);
    float rs = rsqrtf(ss) * SQKE;
    unsigned short bx = f2bf(v.x * rs), by = f2bf(v.y * rs);
    ushort2 st; st.x = bx; st.y = by;
    ((ushort2*)(xn + (size_t)row * DD))[lane] = st;
    float fx = bf2f(bx), fy = bf2f(by);
    float s2 = fx * fx + fy * fy;
    #pragma unroll
    for (int off = 32; off; off >>= 1) s2 += __shfl_xor(s2, off);
    if (lane == 0) sd[row] = s2;
}

// ---- kernel 2: MFMA similarity; LDS-shared B tile, double-buffered ----
// 512 thr = 8 waves; wave owns 64 rows; block covers 512 rows x 256 cols.
// Grid 512; VGPR=128 naturally gives 16 waves/CU = 2 co-resident blocks
// (do NOT force via launch_bounds min-waves: (512,4) halved VGPR -> spills, R7).
__global__ __launch_bounds__(512, 2) void cl_main(const unsigned short* __restrict__ xn,
                                                  const int* __restrict__ labels,
                                                  float* __restrict__ Z,
                                                  float* __restrict__ S) {
    __shared__ __align__(16) unsigned short Bt[2][64][DD];   // 32 KB double buffer

    const int tid  = threadIdx.x;
    const int w    = tid >> 6;
    const int lane = tid & 63;
    const int l15  = lane & 15;
    const int lhi  = lane >> 4;
    const int b    = (int)blockIdx.x;
    const int jr   = b & (JR - 1);
    const int panel = b >> 5;                  // 0..15
    const int row0  = panel * 512 + w * 64;
    const int j0r   = jr * (NN / JR);

    // A frags: lane holds A[row0 + mi*16 + l15][ks*32 + lhi*8 .. +7]
    short8 a[4][4];
    #pragma unroll
    for (int mi = 0; mi < 4; ++mi)
        #pragma unroll
        for (int ks = 0; ks < 4; ++ks)
            a[mi][ks] = *(const short8*)(xn + (size_t)(row0 + mi * 16 + l15) * DD + ks * 32 + lhi * 8);

    int labI[4][4];
    #pragma unroll
    for (int mi = 0; mi < 4; ++mi)
        #pragma unroll
        for (int r = 0; r < 4; ++r)
            labI[mi][r] = labels[row0 + mi * 16 + lhi * 4 + r];

    // staging roles: wave w stages tile rows w*8 .. w*8+7 (two quads of 4 rows)
    // swizzle: LDS slot (row,k) holds global colblk k^(row&7)  (involution)
    const int r4 = lane >> 4, kk = lane & 15;
    const int srow0 = w * 8 + r4;
    const int srow1 = w * 8 + 4 + r4;
    const unsigned short* sg0 = xn + (size_t)(j0r + srow0) * DD + (kk ^ (srow0 & 7)) * 8;
    const unsigned short* sg1 = xn + (size_t)(j0r + srow1) * DD + (kk ^ (srow1 & 7)) * 8;

    float z[4][4], s[4][4];
    #pragma unroll
    for (int mi = 0; mi < 4; ++mi)
        #pragma unroll
        for (int r = 0; r < 4; ++r) { z[mi][r] = 0.f; s[mi][r] = 0.f; }

    // prologue: stage tile 0
    {
        short8 t0 = *(const short8*)sg0;
        short8 t1 = *(const short8*)sg1;
        *(short8*)&Bt[0][srow0][kk * 8] = t0;
        *(short8*)&Bt[0][srow1][kk * 8] = t1;
    }
    __syncthreads();

    const int sw = l15 & 7;
    int cur = 0;
    for (int t8 = 0; t8 < NT; ++t8) {
        const int j0 = j0r + t8 * 64;

        // phase A: issue next tile's global loads (latency hides under compute)
        short8 nx0, nx1;
        if (t8 < NT - 1) {
            nx0 = *(const short8*)(sg0 + (size_t)(t8 + 1) * 64 * DD);
            nx1 = *(const short8*)(sg1 + (size_t)(t8 + 1) * 64 * DD);
        }
        int lj[4];
        #pragma unroll
        for (int ni = 0; ni < 4; ++ni) lj[ni] = labels[j0 + ni * 16 + l15];

        // phase B: compute from Bt[cur]
        const char* rbase = (const char*)&Bt[cur][0][0] + l15 * 256;
        f32x4 acc[4][4];
        #pragma unroll
        for (int mi = 0; mi < 4; ++mi)
            #pragma unroll
            for (int ni = 0; ni < 4; ++ni) acc[mi][ni] = (f32x4){0.f, 0.f, 0.f, 0.f};

        #pragma unroll
        for (int ni = 0; ni < 4; ++ni) {
            short8 bfv[4];
            #pragma unroll
            for (int ks = 0; ks < 4; ++ks)
                bfv[ks] = *(const short8*)(rbase + ni * 4096 + ((((ks << 2) | lhi) ^ sw) << 4));
            #pragma unroll
            for (int ks = 0; ks < 4; ++ks)
                #pragma unroll
                for (int mi = 0; mi < 4; ++mi)
                    acc[mi][ni] = __builtin_amdgcn_mfma_f32_16x16x32_bf16(a[mi][ks], bfv[ks], acc[mi][ni], 0, 0, 0);
        }

        // epilogue: Z += exp2(d); S += d on label match (self removed in fin1)
        #pragma unroll
        for (int mi = 0; mi < 4; ++mi)
            #pragma unroll
            for (int ni = 0; ni < 4; ++ni)
                #pragma unroll
                for (int r = 0; r < 4; ++r) {
                    float d = acc[mi][ni][r];
                    z[mi][r] += __builtin_amdgcn_exp2f(d);
                    s[mi][r] += (lj[ni] == labI[mi][r]) ? d : 0.f;
                }

        // phase C: write staged data into the other buffer
        if (t8 < NT - 1) {
            *(short8*)&Bt[cur ^ 1][srow0][kk * 8] = nx0;
            *(short8*)&Bt[cur ^ 1][srow1][kk * 8] = nx1;
        }
        __syncthreads();
        cur ^= 1;
    }

    // reduce across the 16 col-lanes per row; atomically add into Z/S
    #pragma unroll
    for (int mi = 0; mi < 4; ++mi)
        #pragma unroll
        for (int r = 0; r < 4; ++r) {
            float zz = z[mi][r], ss = s[mi][r];
            #pragma unroll
            for (int off = 1; off < 16; off <<= 1) {
                zz += __shfl_xor(zz, off);
                ss += __shfl_xor(ss, off);
            }
            if (l15 == 0) {
                int row = row0 + mi * 16 + lhi * 4 + r;
                atomicAdd(&Z[row], zz);
                atomicAdd(&S[row], ss);
            }
        }
}

// ---- kernel 3: per-row finalize + per-block partial loss ----
__global__ __launch_bounds__(256) void fin1(const float* __restrict__ Z,
                                            const float* __restrict__ S,
                                            const float* __restrict__ sd,
                                            const int* __restrict__ labels,
                                            float* __restrict__ psum,
                                            float* __restrict__ pcnt) {
    __shared__ int cnt[NCLS];
    __shared__ float rs[4], rc[4];
    const int t = threadIdx.x;
    if (t < NCLS) cnt[t] = 0;
    __syncthreads();
    for (int i = t; i < NN; i += 256) atomicAdd(&cnt[labels[i]], 1);
    __syncthreads();

    const int row = blockIdx.x * 256 + t;
    float Zr = Z[row] - __builtin_amdgcn_exp2f(sd[row]);   // remove self from denominator
    float Sr = S[row] - sd[row];                           // remove self from positive-sum
    int C = cnt[labels[row]] - 1;
    float pr = 0.f, vl = 0.f;
    if (C > 0) { pr = LN2 * Sr / (float)C - logf(Zr); vl = 1.f; }
    #pragma unroll
    for (int off = 32; off; off >>= 1) { pr += __shfl_xor(pr, off); vl += __shfl_xor(vl, off); }
    int wv = t >> 6, ln = t & 63;
    if (ln == 0) { rs[wv] = pr; rc[wv] = vl; }
    __syncthreads();
    if (t == 0) {
        psum[blockIdx.x] = rs[0] + rs[1] + rs[2] + rs[3];
        pcnt[blockIdx.x] = rc[0] + rc[1] + rc[2] + rc[3];
    }
}

__global__ void fin2(const float* __restrict__ psum, const float* __restrict__ pcnt,
                     float* __restrict__ out) {
    int t = threadIdx.x;
    float a = t < 32 ? psum[t] : 0.f;
    float c = t < 32 ? pcnt[t] : 0.f;
    #pragma unroll
    for (int off = 32; off; off >>= 1) { a += __shfl_xor(a, off); c += __shfl_xor(c, off); }
    if (t == 0) out[0] = -a / c;
}

extern "C" void kernel_launch(void* const* d_in, const int* in_sizes, int n_in,
                              void* d_out, int out_size, void* d_ws, size_t ws_size,
                              hipStream_t stream) {
    const float* x      = (const float*)d_in[0];
    const int*   labels = (const int*)d_in[1];
    float* out = (float*)d_out;
    char*  ws  = (char*)d_ws;

    size_t off = 0;
    unsigned short* xn = (unsigned short*)(ws + off); off += (size_t)NN * DD * 2;  // 2 MB
    float* sd = (float*)(ws + off); off += (size_t)NN * 4;                         // 32 KB
    float* zs = (float*)(ws + off); off += (size_t)(2 * NN + 64) * 4;              // 64.25 KB
    float* Z    = zs;
    float* S    = zs + NN;
    float* psum = zs + 2 * NN;
    float* pcnt = zs + 2 * NN + 32;

    prep_kernel<<<NN / 4, 256, 0, stream>>>(x, xn, sd, zs);
    cl_main<<<(NN / 512) * JR, 512, 0, stream>>>(xn, labels, Z, S);
    fin1<<<NN / 256, 256, 0, stream>>>(Z, S, sd, labels, psum, pcnt);
    fin2<<<1, 64, 0, stream>>>(psum, pcnt, out);
}